// Round 1
// baseline (137.046 us; speedup 1.0000x reference)
//
#include <hip/hip_runtime.h>
#include <stdint.h>

#define B_DIM 16384
#define L_DIM 4096
#define H_DIM 256
#define LN_EPS 1e-5f

typedef unsigned short u16;
typedef __attribute__((ext_vector_type(4))) float f32x4;
typedef __attribute__((ext_vector_type(8))) short short8;

__device__ __forceinline__ u16 f2bf(float f) {
  union { float f; uint32_t u; } v; v.f = f;
  uint32_t u = v.u;
  u += 0x7FFFu + ((u >> 16) & 1u);   // round-to-nearest-even
  return (u16)(u >> 16);
}

__device__ __forceinline__ void gload_lds16(const void* g, void* l) {
  __builtin_amdgcn_global_load_lds((const __attribute__((address_space(1))) void*)g,
                                   (__attribute__((address_space(3))) void*)l, 16, 0, 0);
}

// dst[n][k ^ ((n&7)<<3)] = bf16(src[row(k)][n]),  row(k) = idx ? idx[k] : k
// Transpose + cast + pre-swizzle (inverse of the LDS read XOR swizzle).
__global__ __launch_bounds__(256) void prep_tr(const float* __restrict__ src,
                                               const int* __restrict__ idx,
                                               u16* __restrict__ dst,
                                               int Ktot, int srcW) {
  __shared__ u16 tile[64][66];   // +2 pad -> column reads conflict-free
  const int t = threadIdx.x;
  const int k0 = blockIdx.x * 64;
  const int n0 = blockIdx.y * 64;
  for (int r0 = 0; r0 < 64; r0 += 4) {
    const int kk = k0 + r0 + (t >> 6);
    const int nn = n0 + (t & 63);
    const int srow = idx ? idx[kk] : kk;
    tile[r0 + (t >> 6)][t & 63] = f2bf(src[(size_t)srow * srcW + nn]);
  }
  __syncthreads();
  for (int c = t; c < 512; c += 256) {
    const int n = c >> 3;
    const int inner = c & 7;
    const int nG = n0 + n;
    short8 v;
#pragma unroll
    for (int j = 0; j < 8; ++j) v[j] = (short)tile[inner * 8 + j][n];
    const size_t didx = (size_t)nG * Ktot + (size_t)k0 +
                        (size_t)((inner * 8) ^ ((nG & 7) << 3));
    *reinterpret_cast<short8*>(dst + didx) = v;
  }
}

// C[16384,256] = x[16384,4096](fp32->bf16) @ feat[4096,256](bf16, pre-transposed+swizzled)
// BM=32, BN=256(full), BK=64; 256 thr = 4 waves (1x4); per-wave 32x64 -> acc[2][4].
__global__ __launch_bounds__(256, 2) void gemm1(const float* __restrict__ x,
                                                const u16* __restrict__ featT,
                                                u16* __restrict__ h_s) {
  __shared__ __align__(16) u16 As[32 * 64];    // 4 KB, XOR-swizzled rows (128 B)
  __shared__ __align__(16) u16 Bs[256 * 64];   // 32 KB, [n][k] linear (source pre-swizzled)
  const int t = threadIdx.x;
  const int lane = t & 63;
  const int w = t >> 6;
  const int m0 = blockIdx.x * 32;

  const int ar = t >> 3;            // 0..31 : A row
  const int ac = (t & 7) * 8;       // 0..56 : A k-chunk
  const float4* xp4 = reinterpret_cast<const float4*>(x + (size_t)(m0 + ar) * L_DIM + ac);
  const int bn = t >> 3;            // B row within round
  const int binner = (t & 7) * 8;

  float4 a0 = xp4[0], a1 = xp4[1];  // prologue prefetch (kt=0)
  f32x4 acc[2][4] = {};

  for (int kt = 0; kt < 64; ++kt) {
    __syncthreads();                // previous compute done reading LDS
    // B tile: 32 KB via global_load_lds (L2-resident featT)
#pragma unroll
    for (int r = 0; r < 8; ++r) {
      const u16* gp = featT + (size_t)(r * 32 + bn) * L_DIM + (size_t)(kt * 64) + binner;
      gload_lds16(gp, &Bs[(r * 256 + w * 64) * 8]);
    }
    // A tile: convert prefetched fp32 regs -> bf16, swizzled ds_write
    {
      short8 av;
      av[0] = (short)f2bf(a0.x); av[1] = (short)f2bf(a0.y);
      av[2] = (short)f2bf(a0.z); av[3] = (short)f2bf(a0.w);
      av[4] = (short)f2bf(a1.x); av[5] = (short)f2bf(a1.y);
      av[6] = (short)f2bf(a1.z); av[7] = (short)f2bf(a1.w);
      char* ap = reinterpret_cast<char*>(As) + ar * 128 + ((ac * 2) ^ ((ar & 7) << 4));
      *reinterpret_cast<short8*>(ap) = av;
    }
    __syncthreads();                // staging complete (vmcnt+lgkm drained)
    // prefetch next A tile: flies during compute, drained at next top barrier
    {
      const int ktn = (kt < 63) ? (kt + 1) : 63;
      a0 = xp4[ktn * 16];
      a1 = xp4[ktn * 16 + 1];
    }
#pragma unroll
    for (int ks = 0; ks < 2; ++ks) {
      const int kb = ks * 64 + ((lane >> 4) * 16);
      short8 af[2], bf[4];
#pragma unroll
      for (int mi = 0; mi < 2; ++mi) {
        const int row = mi * 16 + (lane & 15);
        af[mi] = *reinterpret_cast<const short8*>(
            reinterpret_cast<const char*>(As) + row * 128 + (kb ^ ((row & 7) << 4)));
      }
#pragma unroll
      for (int ni = 0; ni < 4; ++ni) {
        const int n = w * 64 + ni * 16 + (lane & 15);
        bf[ni] = *reinterpret_cast<const short8*>(
            reinterpret_cast<const char*>(Bs) + n * 128 + (kb ^ ((n & 7) << 4)));
      }
#pragma unroll
      for (int mi = 0; mi < 2; ++mi)
#pragma unroll
        for (int ni = 0; ni < 4; ++ni)
          acc[mi][ni] = __builtin_amdgcn_mfma_f32_16x16x32_bf16(af[mi], bf[ni], acc[mi][ni], 0, 0, 0);
    }
  }
  // epilogue: h_s[row][col ^ ((row&7)<<3)] = bf16(acc)  (pre-swizzled for gemm2)
#pragma unroll
  for (int mi = 0; mi < 2; ++mi) {
#pragma unroll
    for (int r = 0; r < 4; ++r) {
      const int row = m0 + mi * 16 + (lane >> 4) * 4 + r;
      const int swz = (row & 7) << 3;
      u16* hp = h_s + (size_t)row * H_DIM;
#pragma unroll
      for (int ni = 0; ni < 4; ++ni) {
        const int col = w * 64 + ni * 16 + (lane & 15);
        hp[col ^ swz] = f2bf(acc[mi][ni][r]);
      }
    }
  }
}

// out = LayerNorm(relu(h @ W1 + b1)) * gamma + beta
// BM=64, BN=256(full), K=256; 256 thr = 4 waves (1x4); per-wave 64x64 -> acc[4][4].
__global__ __launch_bounds__(256, 1) void gemm2_ln(const u16* __restrict__ h_s,
                                                   const u16* __restrict__ w1T,
                                                   const float* __restrict__ b1,
                                                   const float* __restrict__ gmm,
                                                   const float* __restrict__ bta,
                                                   float* __restrict__ out) {
  __shared__ __align__(16) u16 As[64 * 64];    // 8 KB
  __shared__ __align__(16) u16 Bs[256 * 64];   // 32 KB
  __shared__ float red_s[4][64];
  __shared__ float red_q[4][64];
  __shared__ float mean_s[64];
  __shared__ float rstd_s[64];
  const int t = threadIdx.x;
  const int lane = t & 63;
  const int w = t >> 6;
  const int m0 = blockIdx.x * 64;
  const int bn = t >> 3;
  const int binner = (t & 7) * 8;

  f32x4 acc[4][4] = {};
  for (int kt = 0; kt < 4; ++kt) {
    __syncthreads();
#pragma unroll
    for (int r = 0; r < 2; ++r) {
      const u16* gp = h_s + (size_t)(m0 + r * 32 + bn) * H_DIM + kt * 64 + binner;
      gload_lds16(gp, &As[(r * 256 + w * 64) * 8]);
    }
#pragma unroll
    for (int r = 0; r < 8; ++r) {
      const u16* gp = w1T + (size_t)(r * 32 + bn) * H_DIM + kt * 64 + binner;
      gload_lds16(gp, &Bs[(r * 256 + w * 64) * 8]);
    }
    __syncthreads();
#pragma unroll
    for (int ks = 0; ks < 2; ++ks) {
      const int kb = ks * 64 + ((lane >> 4) * 16);
      short8 af[4], bf[4];
#pragma unroll
      for (int mi = 0; mi < 4; ++mi) {
        const int row = mi * 16 + (lane & 15);
        af[mi] = *reinterpret_cast<const short8*>(
            reinterpret_cast<const char*>(As) + row * 128 + (kb ^ ((row & 7) << 4)));
      }
#pragma unroll
      for (int ni = 0; ni < 4; ++ni) {
        const int n = w * 64 + ni * 16 + (lane & 15);
        bf[ni] = *reinterpret_cast<const short8*>(
            reinterpret_cast<const char*>(Bs) + n * 128 + (kb ^ ((n & 7) << 4)));
      }
#pragma unroll
      for (int mi = 0; mi < 4; ++mi)
#pragma unroll
        for (int ni = 0; ni < 4; ++ni)
          acc[mi][ni] = __builtin_amdgcn_mfma_f32_16x16x32_bf16(af[mi], bf[ni], acc[mi][ni], 0, 0, 0);
    }
  }
  // bias + relu (in place)
  const int cbase = w * 64 + (lane & 15);
  float cb[4];
#pragma unroll
  for (int ni = 0; ni < 4; ++ni) cb[ni] = b1[cbase + ni * 16];
#pragma unroll
  for (int mi = 0; mi < 4; ++mi)
#pragma unroll
    for (int ni = 0; ni < 4; ++ni)
#pragma unroll
      for (int r = 0; r < 4; ++r)
        acc[mi][ni][r] = fmaxf(acc[mi][ni][r] + cb[ni], 0.0f);
  // per-wave row partials (sum, sumsq) over this wave's 64 cols
#pragma unroll
  for (int mi = 0; mi < 4; ++mi) {
#pragma unroll
    for (int r = 0; r < 4; ++r) {
      float s = 0.f, q = 0.f;
#pragma unroll
      for (int ni = 0; ni < 4; ++ni) { const float v = acc[mi][ni][r]; s += v; q += v * v; }
#pragma unroll
      for (int msk = 1; msk < 16; msk <<= 1) { s += __shfl_xor(s, msk); q += __shfl_xor(q, msk); }
      if ((lane & 15) == 0) {
        const int row = mi * 16 + (lane >> 4) * 4 + r;
        red_s[w][row] = s;
        red_q[w][row] = q;
      }
    }
  }
  __syncthreads();
  if (t < 64) {
    const float s = red_s[0][t] + red_s[1][t] + red_s[2][t] + red_s[3][t];
    const float q = red_q[0][t] + red_q[1][t] + red_q[2][t] + red_q[3][t];
    const float mu = s * (1.0f / 256.0f);
    const float var = q * (1.0f / 256.0f) - mu * mu;
    mean_s[t] = mu;
    rstd_s[t] = rsqrtf(var + LN_EPS);
  }
  __syncthreads();
  float cg[4], cbt[4];
#pragma unroll
  for (int ni = 0; ni < 4; ++ni) { cg[ni] = gmm[cbase + ni * 16]; cbt[ni] = bta[cbase + ni * 16]; }
#pragma unroll
  for (int mi = 0; mi < 4; ++mi) {
#pragma unroll
    for (int r = 0; r < 4; ++r) {
      const int row = mi * 16 + (lane >> 4) * 4 + r;
      const float mu = mean_s[row];
      const float rs = rstd_s[row];
      float* op = out + (size_t)(m0 + row) * H_DIM;
#pragma unroll
      for (int ni = 0; ni < 4; ++ni)
        op[cbase + ni * 16] = cg[ni] * (acc[mi][ni][r] - mu) * rs + cbt[ni];
    }
  }
}

extern "C" void kernel_launch(void* const* d_in, const int* in_sizes, int n_in,
                              void* d_out, int out_size, void* d_ws, size_t ws_size,
                              hipStream_t stream) {
  const float* x    = (const float*)d_in[0];
  const float* emb  = (const float*)d_in[1];
  const float* W1   = (const float*)d_in[2];
  const float* b1   = (const float*)d_in[3];
  const float* gmm  = (const float*)d_in[4];
  const float* bta  = (const float*)d_in[5];
  const int*   gidx = (const int*)d_in[6];
  float* out = (float*)d_out;

  char* ws = (char*)d_ws;
  u16* featT = (u16*)ws;                                            // [256][4096] bf16, 2 MB
  u16* w1T   = (u16*)(ws + (size_t)H_DIM * L_DIM * 2);              // [256][256]  bf16, 128 KB
  u16* h_s   = (u16*)(ws + (size_t)H_DIM * L_DIM * 2
                          + (size_t)H_DIM * H_DIM * 2);             // [16384][256] bf16, 8 MB

  prep_tr<<<dim3(L_DIM / 64, H_DIM / 64), 256, 0, stream>>>(emb, gidx, featT, L_DIM, H_DIM);
  prep_tr<<<dim3(H_DIM / 64, H_DIM / 64), 256, 0, stream>>>(W1, nullptr, w1T, H_DIM, H_DIM);
  gemm1<<<dim3(B_DIM / 32), 256, 0, stream>>>(x, featT, h_s);
  gemm2_ln<<<dim3(B_DIM / 64), 256, 0, stream>>>(h_s, w1T, b1, gmm, bta, out);
}